// Round 11
// baseline (344.121 us; speedup 1.0000x reference)
//
#include <hip/hip_runtime.h>
#include <cstdint>
#include <cstddef>

// ---------------------------------------------------------------------------
// Net_25950192402497: 2-layer MLP-message GNN + link-prediction head.
// Identity: segment_sum(concat(x_i,x_j,ef)@W + b) over dst
//   = deg*(h@Wi + b) + (gather-sum h[src])@Wj + (gather-sum ef)@We
// R11: (a) revert R10's half-table gather (XCD heuristic failed: FETCH
// unchanged); (b) int2 elist (one 8B random store in build, not two 4B);
// (c) GEMM K-loop software-pipelined: double-buffered LDS + register
// prefetch so chunk c+1's global loads fly during chunk c's MFMA.
// ---------------------------------------------------------------------------

typedef __attribute__((ext_vector_type(8))) short short8;
typedef __attribute__((ext_vector_type(4))) float float4v;

__device__ __forceinline__ ushort f2b(float f) {
    uint u = __float_as_uint(f);
    u = u + 0x7fff + ((u >> 16) & 1);          // round-to-nearest-even
    return (ushort)(u >> 16);
}
__device__ __forceinline__ float b2f(ushort h) {
    return __uint_as_float(((uint)h) << 16);
}
__device__ __forceinline__ uint pack2(float a, float b) {
    return (uint)f2b(a) | ((uint)f2b(b) << 16);
}

#define F_MSG     1   // X = [deg*A | B | EF | 0] in k-space (Kp=320)
#define F_RELU    2
#define F_DEGBIAS 4
#define F_OUTB    8   // write bf16 output [row][128]
#define F_IN32    16  // A is fp32, convert during staging
#define F_HEAD    32  // no row output; emit z[row] = {za0,za1,zb0,zb1}

#define XS_STRIDE 72  // 144 B rows: max 2-way bank aliasing (free), 16B aligned

// MFMA GEMM: act( X[r,0:Kp] @ W[Kp,128] + bias ).
// Wt bf16 transposed [n=128][Kp], zero-padded; Kp % 64 == 0, Kp/64 <= 5.
// Block: 128 rows x 128 cols, 4 waves; wave w owns rows w*32..w*32+31
// (2 m-subtiles of 16), all 128 cols as 8 col-tiles. acc = 2x8 float4.
// K-loop: double-buffered LDS + reg prefetch (loads overlap MFMA).
__launch_bounds__(256, 2)
__global__ void gemm_mfma(const ushort* __restrict__ A, const ushort* __restrict__ B,
                          const ushort* __restrict__ EF, const float* __restrict__ A32,
                          const float* __restrict__ DEG, const ushort* __restrict__ Wt,
                          const float* __restrict__ bias, ushort* __restrict__ outB,
                          const float* __restrict__ lpW, float* __restrict__ z,
                          int M, int Kp, int flags)
{
    __shared__ ushort xs[2][128 * XS_STRIDE];   // 36 KB
    __shared__ ushort ws[2][128 * XS_STRIDE];   // 36 KB  (total 72 KB -> 2/CU)
    const int tid  = threadIdx.x;
    const int lane = tid & 63;
    const int wave = tid >> 6;
    const int row0 = blockIdx.x << 7;
    const int nch  = Kp >> 6;

    float4v acc[2][8];
#pragma unroll
    for (int m = 0; m < 2; ++m)
#pragma unroll
        for (int t = 0; t < 8; ++t) acc[m][t] = (float4v){0.f, 0.f, 0.f, 0.f};

    const int arow0 = (wave << 5) + (lane & 15);
    const int koff  = (lane >> 4) << 3;
    const int bcol  = lane & 15;

    // per-thread staging slots (idx = tid + j*256 -> n/r = idx>>3, g = idx&7)
    uint4  wreg[4];
    uint4  xreg[4];
    float4 fa[4], fb[4];       // F_IN32 only
    float  dsc[4];             // F_MSG A-region deg

    auto loadW = [&](int kt) {
#pragma unroll
        for (int j = 0; j < 4; ++j) {
            const int idx = tid + j * 256;
            const int n = idx >> 3, g = idx & 7;
            wreg[j] = *(const uint4*)&Wt[(size_t)n * Kp + kt + (g << 3)];
        }
    };
    auto storeW = [&](int b) {
#pragma unroll
        for (int j = 0; j < 4; ++j) {
            const int idx = tid + j * 256;
            const int n = idx >> 3, g = idx & 7;
            *(uint4*)&ws[b][n * XS_STRIDE + (g << 3)] = wreg[j];
        }
    };
    auto loadX = [&](int kt) {
        if (flags & F_MSG) {
            if (kt < 128) {            // region A (deg applied at store)
#pragma unroll
                for (int j = 0; j < 4; ++j) {
                    const int idx = tid + j * 256;
                    const int r = idx >> 3, g = idx & 7;
                    const int gr = row0 + r;
                    if (gr < M) {
                        xreg[j] = *(const uint4*)&A[((size_t)gr << 7) + kt + (g << 3)];
                        dsc[j]  = DEG[gr];
                    } else { xreg[j] = make_uint4(0,0,0,0); dsc[j] = 0.f; }
                }
            } else if (kt < 256) {     // region B
#pragma unroll
                for (int j = 0; j < 4; ++j) {
                    const int idx = tid + j * 256;
                    const int r = idx >> 3, g = idx & 7;
                    const int gr = row0 + r;
                    xreg[j] = (gr < M)
                        ? *(const uint4*)&B[((size_t)gr << 7) + (kt - 128) + (g << 3)]
                        : make_uint4(0,0,0,0);
                }
            } else {                   // region EF (kk 256..271) + zero pad
#pragma unroll
                for (int j = 0; j < 4; ++j) {
                    const int idx = tid + j * 256;
                    const int r = idx >> 3, g = idx & 7;
                    const int gr = row0 + r;
                    xreg[j] = (g < 2 && gr < M)
                        ? *(const uint4*)&EF[((size_t)gr << 4) + (g << 3)]
                        : make_uint4(0,0,0,0);
                }
            }
        } else if (flags & F_IN32) {
#pragma unroll
            for (int j = 0; j < 4; ++j) {
                const int idx = tid + j * 256;
                const int r = idx >> 3, g = idx & 7;
                const int gr = row0 + r;
                if (gr < M) {
                    fa[j] = *(const float4*)&A32[((size_t)gr << 7) + kt + (g << 3)];
                    fb[j] = *(const float4*)&A32[((size_t)gr << 7) + kt + (g << 3) + 4];
                } else {
                    fa[j] = make_float4(0,0,0,0);
                    fb[j] = make_float4(0,0,0,0);
                }
            }
        } else {
#pragma unroll
            for (int j = 0; j < 4; ++j) {
                const int idx = tid + j * 256;
                const int r = idx >> 3, g = idx & 7;
                const int gr = row0 + r;
                xreg[j] = (gr < M)
                    ? *(const uint4*)&A[((size_t)gr << 7) + kt + (g << 3)]
                    : make_uint4(0,0,0,0);
            }
        }
    };
    auto storeX = [&](int b, int kt) {
        if ((flags & F_MSG) && kt < 128) {
#pragma unroll
            for (int j = 0; j < 4; ++j) {
                const int idx = tid + j * 256;
                const int r = idx >> 3, g = idx & 7;
                uint4 a = xreg[j];
                const float d = dsc[j];
                uint* p = (uint*)&a;
#pragma unroll
                for (int q = 0; q < 4; ++q)
                    p[q] = pack2(b2f((ushort)(p[q] & 0xffff)) * d,
                                 b2f((ushort)(p[q] >> 16)) * d);
                *(uint4*)&xs[b][r * XS_STRIDE + (g << 3)] = a;
            }
        } else if (flags & F_IN32) {
#pragma unroll
            for (int j = 0; j < 4; ++j) {
                const int idx = tid + j * 256;
                const int r = idx >> 3, g = idx & 7;
                uint4 v;
                v.x = pack2(fa[j].x, fa[j].y); v.y = pack2(fa[j].z, fa[j].w);
                v.z = pack2(fb[j].x, fb[j].y); v.w = pack2(fb[j].z, fb[j].w);
                *(uint4*)&xs[b][r * XS_STRIDE + (g << 3)] = v;
            }
        } else {
#pragma unroll
            for (int j = 0; j < 4; ++j) {
                const int idx = tid + j * 256;
                const int r = idx >> 3, g = idx & 7;
                *(uint4*)&xs[b][r * XS_STRIDE + (g << 3)] = xreg[j];
            }
        }
    };

    // prologue: fill buffer 0
    loadW(0);
    loadX(0);
    storeW(0);
    storeX(0, 0);
    __syncthreads();

    for (int c = 0; c < nch; ++c) {
        const int cur = c & 1;
        const int ktn = (c + 1) << 6;
        if (c + 1 < nch) { loadW(ktn); loadX(ktn); }   // loads fly during MFMA
#pragma unroll
        for (int s = 0; s < 64; s += 32) {
            const short8 a0 = *(const short8*)&xs[cur][arow0 * XS_STRIDE + s + koff];
            const short8 a1 = *(const short8*)&xs[cur][(arow0 + 16) * XS_STRIDE + s + koff];
#pragma unroll
            for (int t = 0; t < 8; ++t) {
                const short8 bf = *(const short8*)&ws[cur][((t << 4) + bcol) * XS_STRIDE + s + koff];
                acc[0][t] = __builtin_amdgcn_mfma_f32_16x16x32_bf16(a0, bf, acc[0][t], 0, 0, 0);
                acc[1][t] = __builtin_amdgcn_mfma_f32_16x16x32_bf16(a1, bf, acc[1][t], 0, 0, 0);
            }
        }
        if (c + 1 < nch) { storeW(cur ^ 1); storeX(cur ^ 1, ktn); }
        __syncthreads();
    }

    // ---- epilogue: C/D layout col=lane&15, row=(lane>>4)*4+reg ----
    float bcv[8];
#pragma unroll
    for (int t = 0; t < 8; ++t) bcv[t] = bias[(t << 4) + bcol];

    if (flags & F_HEAD) {
        const float2* lw = (const float2*)lpW;
        float2 wa[8], wb[8];
#pragma unroll
        for (int t = 0; t < 8; ++t) {
            const int col = (t << 4) + bcol;
            wa[t] = lw[col];
            wb[t] = lw[128 + col];
        }
#pragma unroll
        for (int m = 0; m < 2; ++m) {
            const int rbase = row0 + (wave << 5) + (m << 4) + ((lane >> 4) << 2);
#pragma unroll
            for (int r = 0; r < 4; ++r) {
                const int row = rbase + r;
                const float d = (row < M) ? DEG[row] : 0.f;
                float za0 = 0.f, za1 = 0.f, zb0 = 0.f, zb1 = 0.f;
#pragma unroll
                for (int t = 0; t < 8; ++t) {
                    const float v = acc[m][t][r] + d * bcv[t];
                    za0 += v * wa[t].x; za1 += v * wa[t].y;
                    zb0 += v * wb[t].x; zb1 += v * wb[t].y;
                }
#pragma unroll
                for (int mk = 8; mk > 0; mk >>= 1) {
                    za0 += __shfl_xor(za0, mk);
                    za1 += __shfl_xor(za1, mk);
                    zb0 += __shfl_xor(zb0, mk);
                    zb1 += __shfl_xor(zb1, mk);
                }
                if (bcol == 0 && row < M)
                    *(float4*)&z[(size_t)row * 4] = make_float4(za0, za1, zb0, zb1);
            }
        }
    } else {
#pragma unroll
        for (int m = 0; m < 2; ++m) {
            const int rbase = row0 + (wave << 5) + (m << 4) + ((lane >> 4) << 2);
#pragma unroll
            for (int t = 0; t < 8; ++t) {
                const int col = (t << 4) + bcol;
#pragma unroll
                for (int r = 0; r < 4; ++r) {
                    const int row = rbase + r;
                    if (row >= M) continue;
                    float v = acc[m][t][r];
                    v += (flags & F_DEGBIAS) ? DEG[row] * bcv[t] : bcv[t];
                    if (flags & F_RELU) v = fmaxf(v, 0.f);
                    outB[((size_t)row << 7) + col] = f2b(v);
                }
            }
        }
    }
}

// ---- prep: zero counts + convert all 4 weight matrices (bf16, T, padded) ----
__launch_bounds__(256)
__global__ void prep(const float* __restrict__ c1pW, const float* __restrict__ c2pW,
                     const float* __restrict__ c1mW, const float* __restrict__ c2mW,
                     ushort* __restrict__ wtp1, ushort* __restrict__ wtp2,
                     ushort* __restrict__ wtm1, ushort* __restrict__ wtm2,
                     int* __restrict__ counts, int N)
{
    const int gtid = blockIdx.x * 256 + threadIdx.x;
    const int gstr = gridDim.x * 256;
    for (int i = gtid; i < N; i += gstr) counts[i] = 0;
    for (int idx = gtid; idx < 128 * 128; idx += gstr) {
        const int n = idx >> 7, k = idx & 127;
        wtp1[idx] = f2b(c1pW[(size_t)k * 128 + n]);
        wtp2[idx] = f2b(c2pW[(size_t)k * 128 + n]);
    }
    for (int idx = gtid; idx < 128 * 320; idx += gstr) {
        const int n = idx / 320, k = idx - n * 320;
        wtm1[idx] = (k < 272) ? f2b(c1mW[(size_t)k * 128 + n]) : (ushort)0;
        wtm2[idx] = (k < 272) ? f2b(c2mW[(size_t)k * 128 + n]) : (ushort)0;
    }
}

__launch_bounds__(256)
__global__ void hist_kernel(const int* __restrict__ ei, int* __restrict__ counts, int E)
{
    const int e = blockIdx.x * 256 + threadIdx.x;
    if (e < E) atomicAdd(&counts[ei[E + e]], 1);
}

__launch_bounds__(256)
__global__ void scan_phase1(const int* __restrict__ counts, int* __restrict__ rowstart,
                            int* __restrict__ blocksums, int N)
{
    __shared__ int sdata[256];
    const int t = threadIdx.x;
    const int i = blockIdx.x * 256 + t;
    const int v = (i < N) ? counts[i] : 0;
    sdata[t] = v;
    __syncthreads();
    for (int off = 1; off < 256; off <<= 1) {
        const int add = (t >= off) ? sdata[t - off] : 0;
        __syncthreads();
        sdata[t] += add;
        __syncthreads();
    }
    if (i < N) rowstart[i] = sdata[t] - v;
    if (t == 255) blocksums[blockIdx.x] = sdata[255];
}

// merged scan phases 2+3: block vb sums blocksums[0..vb) itself (~196 blocks)
__launch_bounds__(256)
__global__ void scan_phase23(const int* __restrict__ counts, const int* __restrict__ bs,
                             int* __restrict__ rowstart, int* __restrict__ cursor,
                             float* __restrict__ degf, int N, int E)
{
    __shared__ int sdata[256];
    const int t = threadIdx.x;
    const int vb = blockIdx.x;
    int part = 0;
    for (int j = t; j < vb; j += 256) part += bs[j];
    sdata[t] = part;
    __syncthreads();
    for (int s = 128; s > 0; s >>= 1) {
        if (t < s) sdata[t] += sdata[t + s];
        __syncthreads();
    }
    const int off = sdata[0];
    const int i = vb * 256 + t;
    if (i < N) {
        const int rs = rowstart[i] + off;
        rowstart[i] = rs;
        cursor[i]   = rs;
        degf[i]     = (float)counts[i];
    }
    if (vb == 0 && t == 0) rowstart[N] = E;
}

__launch_bounds__(256)
__global__ void build_elist(const int* __restrict__ ei, int* __restrict__ cursor,
                            int2* __restrict__ elist, int E)
{
    const int e = blockIdx.x * 256 + threadIdx.x;
    if (e >= E) return;
    const int d = ei[E + e];
    const int pos = atomicAdd(&cursor[d], 1);
    elist[pos] = make_int2(ei[e], e);   // one 8B store to one line
}

// gather: per-node edge sums (R9 shape: 64 lanes/node, full 256B rows)
__launch_bounds__(256)
__global__ void gather(const int2* __restrict__ elist, const int* __restrict__ rowstart,
                       const ushort* __restrict__ h, ushort* __restrict__ agg,
                       const float* __restrict__ ef, ushort* __restrict__ aggef,
                       int N, int doEf)
{
    const int tid = threadIdx.x;
    if (doEf) {
        const int nvb = (N + 15) / 16;
        const int lane16 = tid & 15;
        for (int vb = blockIdx.x; vb < nvb; vb += gridDim.x) {
            const int node = vb * 16 + (tid >> 4);
            if (node >= N) continue;
            const int beg = rowstart[node];
            const int end = rowstart[node + 1];
            float acc = 0.f;
            for (int k = beg; k < end; ++k)
                acc += ef[((size_t)elist[k].y << 4) + lane16];
            aggef[((size_t)node << 4) + lane16] = f2b(acc);
        }
    }
    {
        const int nvb = (N + 3) / 4;
        const int lane = tid & 63;
        const int wave = tid >> 6;
        for (int vb = blockIdx.x; vb < nvb; vb += gridDim.x) {
            const int node = vb * 4 + wave;
            if (node >= N) continue;
            const int beg = rowstart[node];
            const int end = rowstart[node + 1];
            float ax = 0.f, ay = 0.f;
            int k = beg;
            for (; k + 3 < end; k += 4) {
                const int s0 = elist[k].x;
                const int s1 = elist[k + 1].x;
                const int s2 = elist[k + 2].x;
                const int s3 = elist[k + 3].x;
                const uint v0 = *(const uint*)&h[((size_t)s0 << 7) + (lane << 1)];
                const uint v1 = *(const uint*)&h[((size_t)s1 << 7) + (lane << 1)];
                const uint v2 = *(const uint*)&h[((size_t)s2 << 7) + (lane << 1)];
                const uint v3 = *(const uint*)&h[((size_t)s3 << 7) + (lane << 1)];
                ax += b2f((ushort)(v0 & 0xffff)) + b2f((ushort)(v1 & 0xffff))
                    + b2f((ushort)(v2 & 0xffff)) + b2f((ushort)(v3 & 0xffff));
                ay += b2f((ushort)(v0 >> 16)) + b2f((ushort)(v1 >> 16))
                    + b2f((ushort)(v2 >> 16)) + b2f((ushort)(v3 >> 16));
            }
            for (; k < end; ++k) {
                const uint v = *(const uint*)&h[((size_t)elist[k].x << 7) + (lane << 1)];
                ax += b2f((ushort)(v & 0xffff));
                ay += b2f((ushort)(v >> 16));
            }
            *(uint*)&agg[((size_t)node << 7) + (lane << 1)] = pack2(ax, ay);
        }
    }
}

// head: out[q] = z[a].topdot + z[b].botdot + lpb  (z = {za0,za1,zb0,zb1})
__launch_bounds__(256)
__global__ void head_kernel(const float4* __restrict__ z, const int* __restrict__ eli,
                            const float* __restrict__ lpb, float* __restrict__ out, int Q)
{
    const int q = blockIdx.x * 256 + threadIdx.x;
    if (q >= Q) return;
    const int a = eli[q];
    const int b = eli[Q + q];
    const float4 za = z[a];
    const float4 zb = z[b];
    float2 o = make_float2(za.x + zb.z + lpb[0], za.y + zb.w + lpb[1]);
    *(float2*)&out[(size_t)q * 2] = o;
}

extern "C" void kernel_launch(void* const* d_in, const int* in_sizes, int n_in,
                              void* d_out, int out_size, void* d_ws, size_t ws_size,
                              hipStream_t stream)
{
    const float* nf   = (const float*)d_in[0];
    const int*   ei   = (const int*)d_in[1];
    const float* ef   = (const float*)d_in[2];
    const int*   eli  = (const int*)d_in[3];
    const float* c1pW = (const float*)d_in[4];
    const float* c1pb = (const float*)d_in[5];
    const float* c1mW = (const float*)d_in[6];
    const float* c1mb = (const float*)d_in[7];
    const float* c2pW = (const float*)d_in[8];
    const float* c2pb = (const float*)d_in[9];
    const float* c2mW = (const float*)d_in[10];
    const float* c2mb = (const float*)d_in[11];
    const float* lpW  = (const float*)d_in[12];
    const float* lpb  = (const float*)d_in[13];
    float* out = (float*)d_out;

    const int N = in_sizes[0] / 128;
    const int E = in_sizes[1] / 2;
    const int Q = in_sizes[3] / 2;

    // ---- workspace layout ----
    float* DEG = (float*)d_ws;                 // N
    float* z   = DEG + N;                      // N*4 fp32 (head projections)
    int* counts    = (int*)(z + (size_t)N * 4);// N
    int* rowstart  = counts + N;               // N+1
    int* cursor    = rowstart + N + 1;         // N
    int* blocksums = cursor + N;               // 1024 pad
    uintptr_t ep8 = (uintptr_t)(blocksums + 1024);
    ep8 = (ep8 + 7) & ~(uintptr_t)7;
    int2* elist = (int2*)ep8;                  // E int2 (src, edge id)
    uintptr_t up = (uintptr_t)(elist + E);
    up = (up + 15) & ~(uintptr_t)15;
    ushort* h_bf   = (ushort*)up;              // N*128
    ushort* agg_bf = h_bf   + (size_t)N * 128; // N*128
    ushort* x1_bf  = agg_bf + (size_t)N * 128; // N*128
    ushort* ef_bf  = x1_bf  + (size_t)N * 128; // N*16
    ushort* wtp1   = ef_bf  + (size_t)N * 16;  // 128*128
    ushort* wtm1   = wtp1 + 128 * 128;         // 128*320
    ushort* wtp2   = wtm1 + 128 * 320;         // 128*128
    ushort* wtm2   = wtp2 + 128 * 128;         // 128*320

    const int gemmGrid = (N + 127) / 128;
    const int eGrid    = (E + 255) / 256;
    const int nGrid    = (N + 255) / 256;
    const int gGrid    = (N + 3) / 4;
    const int headGrid = (Q + 255) / 256;

    // ---- prep + CSR build ----
    prep<<<nGrid, 256, 0, stream>>>(c1pW, c2pW, c1mW, c2mW, wtp1, wtp2, wtm1, wtm2,
                                    counts, N);
    hist_kernel<<<eGrid, 256, 0, stream>>>(ei, counts, E);
    scan_phase1<<<nGrid, 256, 0, stream>>>(counts, rowstart, blocksums, N);
    scan_phase23<<<nGrid, 256, 0, stream>>>(counts, blocksums, rowstart, cursor, DEG, N, E);
    build_elist<<<eGrid, 256, 0, stream>>>(ei, cursor, elist, E);

    // ---- conv1 ----
    gemm_mfma<<<gemmGrid, 256, 0, stream>>>(nullptr, nullptr, nullptr, nf, DEG, wtp1,
                                            c1pb, h_bf, nullptr, nullptr, N, 128,
                                            F_RELU | F_OUTB | F_IN32);
    gather<<<gGrid, 256, 0, stream>>>(elist, rowstart, h_bf, agg_bf, ef, ef_bf, N, 1);
    gemm_mfma<<<gemmGrid, 256, 0, stream>>>(h_bf, agg_bf, ef_bf, nullptr, DEG, wtm1,
                                            c1mb, x1_bf, nullptr, nullptr, N, 320,
                                            F_MSG | F_RELU | F_DEGBIAS | F_OUTB);

    // ---- conv2 ----
    gemm_mfma<<<gemmGrid, 256, 0, stream>>>(x1_bf, nullptr, nullptr, nullptr, DEG, wtp2,
                                            c2pb, h_bf, nullptr, nullptr, N, 128,
                                            F_RELU | F_OUTB);
    gather<<<gGrid, 256, 0, stream>>>(elist, rowstart, h_bf, agg_bf, nullptr, nullptr, N, 0);
    gemm_mfma<<<gemmGrid, 256, 0, stream>>>(h_bf, agg_bf, ef_bf, nullptr, DEG, wtm2,
                                            c2mb, nullptr, lpW, z, N, 320,
                                            F_MSG | F_DEGBIAS | F_HEAD);

    // ---- head ----
    head_kernel<<<headGrid, 256, 0, stream>>>((const float4*)z, eli, lpb, out, Q);
}

// Round 12
// 327.765 us; speedup vs baseline: 1.0499x; 1.0499x over previous
//
#include <hip/hip_runtime.h>
#include <cstdint>
#include <cstddef>

// ---------------------------------------------------------------------------
// Net_25950192402497: 2-layer MLP-message GNN + link-prediction head.
// Identity: segment_sum(concat(x_i,x_j,ef)@W + b) over dst
//   = deg*(h@Wi + b) + (gather-sum h[src])@Wj + (gather-sum ef)@We
// R12: (a) GEMM reverted to R9 single-buffer form (R11 dbuf: 72KB LDS ->
// 2 blocks/CU, net regression — consistent with the "m97-structure
// pipelining is neutral" HW lesson); (b) gather MLP doubled: 32 lanes/node
// (uint2/lane), unroll-8 -> 16 outstanding 256B row loads per wave vs 4.
// Gather is L2-thrash/latency-bound (FETCH=103MB ~= 0.8*E*256B, 20% hit).
// ---------------------------------------------------------------------------

typedef __attribute__((ext_vector_type(8))) short short8;
typedef __attribute__((ext_vector_type(4))) float float4v;

__device__ __forceinline__ ushort f2b(float f) {
    uint u = __float_as_uint(f);
    u = u + 0x7fff + ((u >> 16) & 1);          // round-to-nearest-even
    return (ushort)(u >> 16);
}
__device__ __forceinline__ float b2f(ushort h) {
    return __uint_as_float(((uint)h) << 16);
}
__device__ __forceinline__ uint pack2(float a, float b) {
    return (uint)f2b(a) | ((uint)f2b(b) << 16);
}

#define F_MSG     1   // X = [deg*A | B | EF | 0] in k-space (Kp=320)
#define F_RELU    2
#define F_DEGBIAS 4
#define F_OUTB    8   // write bf16 output [row][128]
#define F_IN32    16  // A is fp32, convert during staging
#define F_HEAD    32  // no row output; emit z[row] = {za0,za1,zb0,zb1}

#define XS_STRIDE 72  // 144 B rows: max 2-way bank aliasing (free), 16B aligned

// MFMA GEMM (R9 form): act( X[r,0:Kp] @ W[Kp,128] + bias ).
// Wt bf16 transposed [n=128][Kp], zero-padded; Kp % 64 == 0.
// Block: 128 rows x 128 cols, 4 waves; wave w owns rows w*32..w*32+31
// (2 m-subtiles of 16), all 128 cols as 8 col-tiles. acc = 2x8 float4.
__launch_bounds__(256, 2)
__global__ void gemm_mfma(const ushort* __restrict__ A, const ushort* __restrict__ B,
                          const ushort* __restrict__ EF, const float* __restrict__ A32,
                          const float* __restrict__ DEG, const ushort* __restrict__ Wt,
                          const float* __restrict__ bias, ushort* __restrict__ outB,
                          const float* __restrict__ lpW, float* __restrict__ z,
                          int M, int Kp, int flags)
{
    __shared__ ushort xs[128 * XS_STRIDE];   // 18 KB
    __shared__ ushort ws[128 * XS_STRIDE];   // 18 KB
    const int tid  = threadIdx.x;
    const int lane = tid & 63;
    const int wave = tid >> 6;
    const int row0 = blockIdx.x << 7;

    float4v acc[2][8];
#pragma unroll
    for (int m = 0; m < 2; ++m)
#pragma unroll
        for (int t = 0; t < 8; ++t) acc[m][t] = (float4v){0.f, 0.f, 0.f, 0.f};

    const int arow0 = (wave << 5) + (lane & 15);
    const int koff  = (lane >> 4) << 3;
    const int bcol  = lane & 15;

    for (int kt = 0; kt < Kp; kt += 64) {
        __syncthreads();
        for (int idx = tid; idx < 128 * 8; idx += 256) {
            const int n = idx >> 3;
            const int g = idx & 7;
            const uint4 v = *(const uint4*)&Wt[(size_t)n * Kp + kt + (g << 3)];
            *(uint4*)&ws[n * XS_STRIDE + (g << 3)] = v;
        }
        if (flags & F_MSG) {
            for (int idx = tid; idx < 128 * 8; idx += 256) {
                const int r  = idx >> 3;
                const int g  = idx & 7;
                const int gr = row0 + r;
                const int kk = kt + (g << 3);
                uint4 v = make_uint4(0, 0, 0, 0);
                if (gr < M) {
                    if (kk < 128) {                       // deg * A
                        uint4 a = *(const uint4*)&A[((size_t)gr << 7) + kk];
                        const float d = DEG[gr];
                        uint* p = (uint*)&a;
#pragma unroll
                        for (int q = 0; q < 4; ++q)
                            p[q] = pack2(b2f((ushort)(p[q] & 0xffff)) * d,
                                         b2f((ushort)(p[q] >> 16)) * d);
                        v = a;
                    } else if (kk < 256) {                // B
                        v = *(const uint4*)&B[((size_t)gr << 7) + kk - 128];
                    } else if (kk < 272) {                // EF
                        v = *(const uint4*)&EF[((size_t)gr << 4) + kk - 256];
                    }
                }
                *(uint4*)&xs[r * XS_STRIDE + (g << 3)] = v;
            }
        } else if (flags & F_IN32) {
            for (int idx = tid; idx < 128 * 8; idx += 256) {
                const int r  = idx >> 3;
                const int g  = idx & 7;
                const int gr = row0 + r;
                uint4 v = make_uint4(0, 0, 0, 0);
                if (gr < M) {
                    const float4 f0 = *(const float4*)&A32[((size_t)gr << 7) + kt + (g << 3)];
                    const float4 f1 = *(const float4*)&A32[((size_t)gr << 7) + kt + (g << 3) + 4];
                    v.x = pack2(f0.x, f0.y); v.y = pack2(f0.z, f0.w);
                    v.z = pack2(f1.x, f1.y); v.w = pack2(f1.z, f1.w);
                }
                *(uint4*)&xs[r * XS_STRIDE + (g << 3)] = v;
            }
        } else {
            for (int idx = tid; idx < 128 * 8; idx += 256) {
                const int r  = idx >> 3;
                const int g  = idx & 7;
                const int gr = row0 + r;
                uint4 v = make_uint4(0, 0, 0, 0);
                if (gr < M) v = *(const uint4*)&A[((size_t)gr << 7) + kt + (g << 3)];
                *(uint4*)&xs[r * XS_STRIDE + (g << 3)] = v;
            }
        }
        __syncthreads();
#pragma unroll
        for (int s = 0; s < 64; s += 32) {
            const short8 a0 = *(const short8*)&xs[arow0 * XS_STRIDE + s + koff];
            const short8 a1 = *(const short8*)&xs[(arow0 + 16) * XS_STRIDE + s + koff];
#pragma unroll
            for (int t = 0; t < 8; ++t) {
                const short8 bf = *(const short8*)&ws[((t << 4) + bcol) * XS_STRIDE + s + koff];
                acc[0][t] = __builtin_amdgcn_mfma_f32_16x16x32_bf16(a0, bf, acc[0][t], 0, 0, 0);
                acc[1][t] = __builtin_amdgcn_mfma_f32_16x16x32_bf16(a1, bf, acc[1][t], 0, 0, 0);
            }
        }
    }

    // ---- epilogue: C/D layout col=lane&15, row=(lane>>4)*4+reg ----
    float bcv[8];
#pragma unroll
    for (int t = 0; t < 8; ++t) bcv[t] = bias[(t << 4) + bcol];

    if (flags & F_HEAD) {
        const float2* lw = (const float2*)lpW;
        float2 wa[8], wb[8];
#pragma unroll
        for (int t = 0; t < 8; ++t) {
            const int col = (t << 4) + bcol;
            wa[t] = lw[col];
            wb[t] = lw[128 + col];
        }
#pragma unroll
        for (int m = 0; m < 2; ++m) {
            const int rbase = row0 + (wave << 5) + (m << 4) + ((lane >> 4) << 2);
#pragma unroll
            for (int r = 0; r < 4; ++r) {
                const int row = rbase + r;
                const float d = (row < M) ? DEG[row] : 0.f;
                float za0 = 0.f, za1 = 0.f, zb0 = 0.f, zb1 = 0.f;
#pragma unroll
                for (int t = 0; t < 8; ++t) {
                    const float v = acc[m][t][r] + d * bcv[t];
                    za0 += v * wa[t].x; za1 += v * wa[t].y;
                    zb0 += v * wb[t].x; zb1 += v * wb[t].y;
                }
#pragma unroll
                for (int mk = 8; mk > 0; mk >>= 1) {
                    za0 += __shfl_xor(za0, mk);
                    za1 += __shfl_xor(za1, mk);
                    zb0 += __shfl_xor(zb0, mk);
                    zb1 += __shfl_xor(zb1, mk);
                }
                if (bcol == 0 && row < M)
                    *(float4*)&z[(size_t)row * 4] = make_float4(za0, za1, zb0, zb1);
            }
        }
    } else {
#pragma unroll
        for (int m = 0; m < 2; ++m) {
            const int rbase = row0 + (wave << 5) + (m << 4) + ((lane >> 4) << 2);
#pragma unroll
            for (int t = 0; t < 8; ++t) {
                const int col = (t << 4) + bcol;
#pragma unroll
                for (int r = 0; r < 4; ++r) {
                    const int row = rbase + r;
                    if (row >= M) continue;
                    float v = acc[m][t][r];
                    v += (flags & F_DEGBIAS) ? DEG[row] * bcv[t] : bcv[t];
                    if (flags & F_RELU) v = fmaxf(v, 0.f);
                    outB[((size_t)row << 7) + col] = f2b(v);
                }
            }
        }
    }
}

// ---- prep: zero counts + convert all 4 weight matrices (bf16, T, padded) ----
__launch_bounds__(256)
__global__ void prep(const float* __restrict__ c1pW, const float* __restrict__ c2pW,
                     const float* __restrict__ c1mW, const float* __restrict__ c2mW,
                     ushort* __restrict__ wtp1, ushort* __restrict__ wtp2,
                     ushort* __restrict__ wtm1, ushort* __restrict__ wtm2,
                     int* __restrict__ counts, int N)
{
    const int gtid = blockIdx.x * 256 + threadIdx.x;
    const int gstr = gridDim.x * 256;
    for (int i = gtid; i < N; i += gstr) counts[i] = 0;
    for (int idx = gtid; idx < 128 * 128; idx += gstr) {
        const int n = idx >> 7, k = idx & 127;
        wtp1[idx] = f2b(c1pW[(size_t)k * 128 + n]);
        wtp2[idx] = f2b(c2pW[(size_t)k * 128 + n]);
    }
    for (int idx = gtid; idx < 128 * 320; idx += gstr) {
        const int n = idx / 320, k = idx - n * 320;
        wtm1[idx] = (k < 272) ? f2b(c1mW[(size_t)k * 128 + n]) : (ushort)0;
        wtm2[idx] = (k < 272) ? f2b(c2mW[(size_t)k * 128 + n]) : (ushort)0;
    }
}

__launch_bounds__(256)
__global__ void hist_kernel(const int* __restrict__ ei, int* __restrict__ counts, int E)
{
    const int e = blockIdx.x * 256 + threadIdx.x;
    if (e < E) atomicAdd(&counts[ei[E + e]], 1);
}

__launch_bounds__(256)
__global__ void scan_phase1(const int* __restrict__ counts, int* __restrict__ rowstart,
                            int* __restrict__ blocksums, int N)
{
    __shared__ int sdata[256];
    const int t = threadIdx.x;
    const int i = blockIdx.x * 256 + t;
    const int v = (i < N) ? counts[i] : 0;
    sdata[t] = v;
    __syncthreads();
    for (int off = 1; off < 256; off <<= 1) {
        const int add = (t >= off) ? sdata[t - off] : 0;
        __syncthreads();
        sdata[t] += add;
        __syncthreads();
    }
    if (i < N) rowstart[i] = sdata[t] - v;
    if (t == 255) blocksums[blockIdx.x] = sdata[255];
}

// merged scan phases 2+3: block vb sums blocksums[0..vb) itself (~196 blocks)
__launch_bounds__(256)
__global__ void scan_phase23(const int* __restrict__ counts, const int* __restrict__ bs,
                             int* __restrict__ rowstart, int* __restrict__ cursor,
                             float* __restrict__ degf, int N, int E)
{
    __shared__ int sdata[256];
    const int t = threadIdx.x;
    const int vb = blockIdx.x;
    int part = 0;
    for (int j = t; j < vb; j += 256) part += bs[j];
    sdata[t] = part;
    __syncthreads();
    for (int s = 128; s > 0; s >>= 1) {
        if (t < s) sdata[t] += sdata[t + s];
        __syncthreads();
    }
    const int off = sdata[0];
    const int i = vb * 256 + t;
    if (i < N) {
        const int rs = rowstart[i] + off;
        rowstart[i] = rs;
        cursor[i]   = rs;
        degf[i]     = (float)counts[i];
    }
    if (vb == 0 && t == 0) rowstart[N] = E;
}

__launch_bounds__(256)
__global__ void build_elist(const int* __restrict__ ei, int* __restrict__ cursor,
                            int2* __restrict__ elist, int E)
{
    const int e = blockIdx.x * 256 + threadIdx.x;
    if (e >= E) return;
    const int d = ei[E + e];
    const int pos = atomicAdd(&cursor[d], 1);
    elist[pos] = make_int2(ei[e], e);
}

// gather: 32 lanes per node (2 nodes/wave), uint2 (8B) per lane per edge,
// unroll-8 -> 16 outstanding 256B row loads per wave.
__launch_bounds__(256)
__global__ void gather(const int2* __restrict__ elist, const int* __restrict__ rowstart,
                       const ushort* __restrict__ h, ushort* __restrict__ agg,
                       const float* __restrict__ ef, ushort* __restrict__ aggef,
                       int N, int doEf)
{
    const int tid = threadIdx.x;
    if (doEf) {
        const int nvb = (N + 15) / 16;
        const int lane16 = tid & 15;
        for (int vb = blockIdx.x; vb < nvb; vb += gridDim.x) {
            const int node = vb * 16 + (tid >> 4);
            if (node >= N) continue;
            const int beg = rowstart[node];
            const int end = rowstart[node + 1];
            float acc = 0.f;
            for (int k = beg; k < end; ++k)
                acc += ef[((size_t)elist[k].y << 4) + lane16];
            aggef[((size_t)node << 4) + lane16] = f2b(acc);
        }
    }
    {
        const int nvb = (N + 7) / 8;       // 8 nodes per block
        const int grp = tid >> 5;          // 0..7
        const int l   = tid & 31;
        for (int vb = blockIdx.x; vb < nvb; vb += gridDim.x) {
            const int node = vb * 8 + grp;
            if (node >= N) continue;
            const int beg = rowstart[node];
            const int end = rowstart[node + 1];
            float a0 = 0.f, a1 = 0.f, a2 = 0.f, a3 = 0.f;
            int k = beg;
            for (; k + 7 < end; k += 8) {
                uint2 v[8];
#pragma unroll
                for (int j = 0; j < 8; ++j) {
                    const int s = elist[k + j].x;
                    v[j] = *(const uint2*)&h[((size_t)s << 7) + (l << 2)];
                }
#pragma unroll
                for (int j = 0; j < 8; ++j) {
                    a0 += b2f((ushort)(v[j].x & 0xffff));
                    a1 += b2f((ushort)(v[j].x >> 16));
                    a2 += b2f((ushort)(v[j].y & 0xffff));
                    a3 += b2f((ushort)(v[j].y >> 16));
                }
            }
            for (; k < end; ++k) {
                const uint2 v = *(const uint2*)&h[((size_t)elist[k].x << 7) + (l << 2)];
                a0 += b2f((ushort)(v.x & 0xffff));
                a1 += b2f((ushort)(v.x >> 16));
                a2 += b2f((ushort)(v.y & 0xffff));
                a3 += b2f((ushort)(v.y >> 16));
            }
            uint2 o;
            o.x = pack2(a0, a1);
            o.y = pack2(a2, a3);
            *(uint2*)&agg[((size_t)node << 7) + (l << 2)] = o;
        }
    }
}

// head: out[q] = z[a].topdot + z[b].botdot + lpb  (z = {za0,za1,zb0,zb1})
__launch_bounds__(256)
__global__ void head_kernel(const float4* __restrict__ z, const int* __restrict__ eli,
                            const float* __restrict__ lpb, float* __restrict__ out, int Q)
{
    const int q = blockIdx.x * 256 + threadIdx.x;
    if (q >= Q) return;
    const int a = eli[q];
    const int b = eli[Q + q];
    const float4 za = z[a];
    const float4 zb = z[b];
    float2 o = make_float2(za.x + zb.z + lpb[0], za.y + zb.w + lpb[1]);
    *(float2*)&out[(size_t)q * 2] = o;
}

extern "C" void kernel_launch(void* const* d_in, const int* in_sizes, int n_in,
                              void* d_out, int out_size, void* d_ws, size_t ws_size,
                              hipStream_t stream)
{
    const float* nf   = (const float*)d_in[0];
    const int*   ei   = (const int*)d_in[1];
    const float* ef   = (const float*)d_in[2];
    const int*   eli  = (const int*)d_in[3];
    const float* c1pW = (const float*)d_in[4];
    const float* c1pb = (const float*)d_in[5];
    const float* c1mW = (const float*)d_in[6];
    const float* c1mb = (const float*)d_in[7];
    const float* c2pW = (const float*)d_in[8];
    const float* c2pb = (const float*)d_in[9];
    const float* c2mW = (const float*)d_in[10];
    const float* c2mb = (const float*)d_in[11];
    const float* lpW  = (const float*)d_in[12];
    const float* lpb  = (const float*)d_in[13];
    float* out = (float*)d_out;

    const int N = in_sizes[0] / 128;
    const int E = in_sizes[1] / 2;
    const int Q = in_sizes[3] / 2;

    // ---- workspace layout ----
    float* DEG = (float*)d_ws;                 // N
    float* z   = DEG + N;                      // N*4 fp32 (head projections)
    int* counts    = (int*)(z + (size_t)N * 4);// N
    int* rowstart  = counts + N;               // N+1
    int* cursor    = rowstart + N + 1;         // N
    int* blocksums = cursor + N;               // 1024 pad
    uintptr_t ep8 = (uintptr_t)(blocksums + 1024);
    ep8 = (ep8 + 7) & ~(uintptr_t)7;
    int2* elist = (int2*)ep8;                  // E int2 (src, edge id)
    uintptr_t up = (uintptr_t)(elist + E);
    up = (up + 15) & ~(uintptr_t)15;
    ushort* h_bf   = (ushort*)up;              // N*128
    ushort* agg_bf = h_bf   + (size_t)N * 128; // N*128
    ushort* x1_bf  = agg_bf + (size_t)N * 128; // N*128
    ushort* ef_bf  = x1_bf  + (size_t)N * 128; // N*16
    ushort* wtp1   = ef_bf  + (size_t)N * 16;  // 128*128
    ushort* wtm1   = wtp1 + 128 * 128;         // 128*320
    ushort* wtp2   = wtm1 + 128 * 320;         // 128*128
    ushort* wtm2   = wtp2 + 128 * 128;         // 128*320

    const int gemmGrid = (N + 127) / 128;
    const int eGrid    = (E + 255) / 256;
    const int nGrid    = (N + 255) / 256;
    const int gGrid    = (N + 7) / 8;
    const int headGrid = (Q + 255) / 256;

    // ---- prep + CSR build ----
    prep<<<nGrid, 256, 0, stream>>>(c1pW, c2pW, c1mW, c2mW, wtp1, wtp2, wtm1, wtm2,
                                    counts, N);
    hist_kernel<<<eGrid, 256, 0, stream>>>(ei, counts, E);
    scan_phase1<<<nGrid, 256, 0, stream>>>(counts, rowstart, blocksums, N);
    scan_phase23<<<nGrid, 256, 0, stream>>>(counts, blocksums, rowstart, cursor, DEG, N, E);
    build_elist<<<eGrid, 256, 0, stream>>>(ei, cursor, elist, E);

    // ---- conv1 ----
    gemm_mfma<<<gemmGrid, 256, 0, stream>>>(nullptr, nullptr, nullptr, nf, DEG, wtp1,
                                            c1pb, h_bf, nullptr, nullptr, N, 128,
                                            F_RELU | F_OUTB | F_IN32);
    gather<<<gGrid, 256, 0, stream>>>(elist, rowstart, h_bf, agg_bf, ef, ef_bf, N, 1);
    gemm_mfma<<<gemmGrid, 256, 0, stream>>>(h_bf, agg_bf, ef_bf, nullptr, DEG, wtm1,
                                            c1mb, x1_bf, nullptr, nullptr, N, 320,
                                            F_MSG | F_RELU | F_DEGBIAS | F_OUTB);

    // ---- conv2 ----
    gemm_mfma<<<gemmGrid, 256, 0, stream>>>(x1_bf, nullptr, nullptr, nullptr, DEG, wtp2,
                                            c2pb, h_bf, nullptr, nullptr, N, 128,
                                            F_RELU | F_OUTB);
    gather<<<gGrid, 256, 0, stream>>>(elist, rowstart, h_bf, agg_bf, nullptr, nullptr, N, 0);
    gemm_mfma<<<gemmGrid, 256, 0, stream>>>(h_bf, agg_bf, ef_bf, nullptr, DEG, wtm2,
                                            c2mb, nullptr, lpW, z, N, 320,
                                            F_MSG | F_DEGBIAS | F_HEAD);

    // ---- head ----
    head_kernel<<<headGrid, 256, 0, stream>>>((const float4*)z, eli, lpb, out, Q);
}